// Round 1
// baseline (565.630 us; speedup 1.0000x reference)
//
#include <hip/hip_runtime.h>

// ECNR forward: 256 MLPs, codebook-dequantized weights, 4 layers
// (16->128->128->128->1), sin(30x) activations on layers 0-2.
// Grid: 8192 blocks = 256 samples x 32 point-tiles (64 pts each), 256 thr.
// fp32 vector-ALU GEMM (no fp32 MFMA on CDNA4); weights dequantized into
// LDS panels from int32 labels + 256-entry centroid table.

#define NTHREADS 256

// sin(30*pre) with fp32 Cody-Waite reduction to [-pi,pi] then native sin.
// 2-term 2*pi split: C1 = fp32(2pi), C2 = 2pi - C1 = -1.7484556e-7.
__device__ __forceinline__ float sin_omega(float pre) {
    float x = 30.0f * pre;                        // matches reference rounding
    float k = __builtin_rintf(x * 0.15915494309189535f);
    float r = __builtin_fmaf(k, -6.2831854820251465f, x);
    r = __builtin_fmaf(k, 1.7484556e-07f, r);     // r in [-pi, pi], err ~3e-7
    return __sinf(r);                             // small-arg native sin
}

__global__ __launch_bounds__(NTHREADS, 3)
void ecnr_fwd(const float* __restrict__ x,
              const int*   __restrict__ mlp_idx,
              const int*   __restrict__ block_idx,
              const float* __restrict__ latent,
              const float* __restrict__ cent0, const int* __restrict__ lab0, const float* __restrict__ bias0,
              const float* __restrict__ cent1, const int* __restrict__ lab1, const float* __restrict__ bias1,
              const float* __restrict__ cent2, const int* __restrict__ lab2, const float* __restrict__ bias2,
              const float* __restrict__ cent3, const int* __restrict__ lab3, const float* __restrict__ bias3,
              float* __restrict__ out)
{
    // 50 KB static LDS -> 3 blocks/CU (12 waves/CU)
    __shared__ __attribute__((aligned(16))) float hT[128][64];   // 32 KB, [channel][point]
    __shared__ __attribute__((aligned(16))) float wbuf[4096];    // 16 KB: L0 {W0[16][128] @0, inT[16][64] @2048}; L1/2 panel[32][128]; L3 partials
    __shared__ __attribute__((aligned(16))) float centS[256];    // current layer codebook
    __shared__ __attribute__((aligned(16))) float biasS[128];
    __shared__ __attribute__((aligned(16))) float w3S[128];

    const int t    = threadIdx.x;
    const int b    = blockIdx.x >> 5;      // sample
    const int tile = blockIdx.x & 31;
    const int p0   = tile * 64;
    const int mlp  = mlp_idx[b];

    const int pg = t & 15;                 // 16 point-groups of 4 points
    const int cg = t >> 4;                 // 16 channel-groups of 8 channels
    const int pb = pg * 4;
    const int cb = cg * 8;

    // ---- stage: centroids(l0), input tile (x + latent), bias0 ----
    centS[t] = cent0[t];
    if (t < 64) {
        const float* xp = x + (size_t)(b * 2048 + p0 + t) * 3;
        wbuf[2048 + 0 * 64 + t] = xp[0];
        wbuf[2048 + 1 * 64 + t] = xp[1];
        wbuf[2048 + 2 * 64 + t] = xp[2];
    } else {
        const int zb = block_idx[b];
        const float* zp = latent + ((size_t)mlp * 8 + zb) * 13;
        for (int f = t - 64; f < 13 * 64; f += 192) {
            const int i = f >> 6;
            const int p = f & 63;
            wbuf[2048 + (3 + i) * 64 + p] = zp[i];
        }
    }
    if (t < 128) biasS[t] = bias0[mlp * 128 + t];
    __syncthreads();

    // ---- dequant W0 (16x128) into wbuf[0..2048) ----
    {
        const int4* l4 = (const int4*)(lab0 + (size_t)mlp * 2048);
        #pragma unroll
        for (int u = 0; u < 2; ++u) {
            const int4 lv = l4[u * 256 + t];
            float4 wv;
            wv.x = centS[lv.x]; wv.y = centS[lv.y];
            wv.z = centS[lv.z]; wv.w = centS[lv.w];
            *(float4*)&wbuf[(u * 256 + t) * 4] = wv;
        }
    }
    __syncthreads();

    // ---- layer 0: [64x16] @ [16x128], + bias, sin ----
    float acc[4][8];
    {
        float bj[8];
        #pragma unroll
        for (int j = 0; j < 8; ++j) bj[j] = biasS[cb + j];
        #pragma unroll
        for (int p = 0; p < 4; ++p)
            #pragma unroll
            for (int j = 0; j < 8; ++j) acc[p][j] = bj[j];
    }
    #pragma unroll
    for (int k = 0; k < 16; ++k) {
        const float4 hv = *(const float4*)&wbuf[2048 + k * 64 + pb];
        const float4 wa = *(const float4*)&wbuf[k * 128 + cb];
        const float4 wb = *(const float4*)&wbuf[k * 128 + cb + 4];
        const float h[4] = {hv.x, hv.y, hv.z, hv.w};
        const float w[8] = {wa.x, wa.y, wa.z, wa.w, wb.x, wb.y, wb.z, wb.w};
        #pragma unroll
        for (int p = 0; p < 4; ++p)
            #pragma unroll
            for (int j = 0; j < 8; ++j)
                acc[p][j] = __builtin_fmaf(h[p], w[j], acc[p][j]);
    }
    #pragma unroll
    for (int j = 0; j < 8; ++j) {   // exclusive hT slots; next sync publishes
        float4 hv;
        hv.x = sin_omega(acc[0][j]);
        hv.y = sin_omega(acc[1][j]);
        hv.z = sin_omega(acc[2][j]);
        hv.w = sin_omega(acc[3][j]);
        *(float4*)&hT[cb + j][pb] = hv;
    }

    // ---- layers 1 and 2: [64x128] @ [128x128], + bias, sin ----
    const int*   labs[2]   = {lab1, lab2};
    const float* cents[2]  = {cent1, cent2};
    const float* biases[2] = {bias1, bias2};
    #pragma unroll
    for (int L = 0; L < 2; ++L) {
        __syncthreads();                       // hT writes + prior wbuf/centS reads done
        centS[t] = cents[L][t];
        if (t < 128) biasS[t] = biases[L][mlp * 128 + t];
        __syncthreads();

        float bj[8];
        #pragma unroll
        for (int j = 0; j < 8; ++j) bj[j] = biasS[cb + j];
        float a2[4][8];
        #pragma unroll
        for (int p = 0; p < 4; ++p)
            #pragma unroll
            for (int j = 0; j < 8; ++j) a2[p][j] = bj[j];

        const int4* l4 = (const int4*)(labs[L] + (size_t)mlp * 16384);
        for (int kp = 0; kp < 4; ++kp) {       // 4 k-panels of 32
            if (kp) __syncthreads();           // prior panel reads done
            #pragma unroll
            for (int u = 0; u < 4; ++u) {
                const int4 lv = l4[kp * 1024 + u * 256 + t];
                float4 wv;
                wv.x = centS[lv.x]; wv.y = centS[lv.y];
                wv.z = centS[lv.z]; wv.w = centS[lv.w];
                *(float4*)&wbuf[(u * 256 + t) * 4] = wv;
            }
            __syncthreads();
            #pragma unroll 8
            for (int kk = 0; kk < 32; ++kk) {
                const float4 hv = *(const float4*)&hT[kp * 32 + kk][pb];
                const float4 wa = *(const float4*)&wbuf[kk * 128 + cb];
                const float4 wb = *(const float4*)&wbuf[kk * 128 + cb + 4];
                const float h[4] = {hv.x, hv.y, hv.z, hv.w};
                const float w[8] = {wa.x, wa.y, wa.z, wa.w, wb.x, wb.y, wb.z, wb.w};
                #pragma unroll
                for (int p = 0; p < 4; ++p)
                    #pragma unroll
                    for (int j = 0; j < 8; ++j)
                        a2[p][j] = __builtin_fmaf(h[p], w[j], a2[p][j]);
            }
        }
        __syncthreads();                       // all hT reads done -> safe overwrite
        #pragma unroll
        for (int j = 0; j < 8; ++j) {
            float4 hv;
            hv.x = sin_omega(a2[0][j]);
            hv.y = sin_omega(a2[1][j]);
            hv.z = sin_omega(a2[2][j]);
            hv.w = sin_omega(a2[3][j]);
            *(float4*)&hT[cb + j][pb] = hv;
        }
    }

    // ---- layer 3: [64x128] @ [128x1] + bias (no sin) ----
    __syncthreads();                           // layer-2 hT visible
    centS[t] = cent3[t];
    __syncthreads();
    if (t < 32) {
        const int4 lv = ((const int4*)(lab3 + (size_t)mlp * 128))[t];
        float4 wv;
        wv.x = centS[lv.x]; wv.y = centS[lv.y];
        wv.z = centS[lv.z]; wv.w = centS[lv.w];
        *(float4*)&w3S[t * 4] = wv;
    }
    __syncthreads();
    {
        const int p = t & 63;
        const int q = t >> 6;                  // 4-way k-split across waves
        float s = 0.0f;
        #pragma unroll 8
        for (int i = 0; i < 32; ++i)
            s = __builtin_fmaf(hT[q * 32 + i][p], w3S[q * 32 + i], s);
        wbuf[q * 64 + p] = s;
    }
    __syncthreads();
    if (t < 64) {
        const float o = wbuf[t] + wbuf[64 + t] + wbuf[128 + t] + wbuf[192 + t]
                      + bias3[mlp];
        out[(size_t)b * 2048 + p0 + t] = o;
    }
}

extern "C" void kernel_launch(void* const* d_in, const int* in_sizes, int n_in,
                              void* d_out, int out_size, void* d_ws, size_t ws_size,
                              hipStream_t stream) {
    (void)in_sizes; (void)n_in; (void)d_ws; (void)ws_size; (void)out_size;
    ecnr_fwd<<<8192, NTHREADS, 0, stream>>>(
        (const float*)d_in[0],  (const int*)d_in[1],  (const int*)d_in[2],
        (const float*)d_in[3],
        (const float*)d_in[4],  (const int*)d_in[5],  (const float*)d_in[6],
        (const float*)d_in[7],  (const int*)d_in[8],  (const float*)d_in[9],
        (const float*)d_in[10], (const int*)d_in[11], (const float*)d_in[12],
        (const float*)d_in[13], (const int*)d_in[14], (const float*)d_in[15],
        (float*)d_out);
}

// Round 3
// 471.986 us; speedup vs baseline: 1.1984x; 1.1984x over previous
//
#include <hip/hip_runtime.h>

// ECNR forward, MFMA version: layers 1,2 (128x128 GEMMs) on
// v_mfma_f32_32x32x16_bf16 with bf16x3 split-precision (6 products,
// fp32-equivalent accuracy). Layers 0 (K=16) and 3 (fo=1) on VALU fp32.
// Grid: 4096 blocks = 256 samples x 16 point-tiles (128 pts), 512 threads.
// LDS 136 KB/block (gfx950: 160 KB addressable), 1 block/CU, 8 waves.
// R3 fix: bias2 staging index was (t-384) -> negative; now (t-256).

#define NT 512

typedef __bf16 v8bf __attribute__((ext_vector_type(8)));
typedef float v16f __attribute__((ext_vector_type(16)));

#define MFMA(a, b, c) __builtin_amdgcn_mfma_f32_32x32x16_bf16(a, b, c, 0, 0, 0)

// sin(30*pre), Cody-Waite 2-term reduction to [-pi,pi] + native sin.
__device__ __forceinline__ float sin_omega(float pre) {
    float x = 30.0f * pre;
    float k = __builtin_rintf(x * 0.15915494309189535f);
    float r = __builtin_fmaf(k, -6.2831854820251465f, x);
    r = __builtin_fmaf(k, 1.7484556e-07f, r);
    return __sinf(r);
}

__device__ __forceinline__ void split3(float c, unsigned& u0, unsigned& u1, unsigned& u2) {
    __bf16 b0 = (__bf16)c; float f0 = (float)b0;
    float r1 = c - f0;
    __bf16 b1 = (__bf16)r1; float f1 = (float)b1;
    float r2 = r1 - f1;
    __bf16 b2 = (__bf16)r2;
    u0 = (unsigned)__builtin_bit_cast(unsigned short, b0);
    u1 = (unsigned)__builtin_bit_cast(unsigned short, b1);
    u2 = (unsigned)__builtin_bit_cast(unsigned short, b2);
}

// LDS layout (bytes):
//   H      [128][132] f32   @ 0       67584   (activations, padded stride 132)
//   WT     [2][3][128][40]  @ 67584   61440   (split W^T panels, bf16, stride 40)
//     overlay: W0s[16][128] f32 @67584, inT[16][128] f32 @75776
//   centPak[2][256] uint2   @ 129024  4096    (pre-split packed codebooks L1,L2)
//   centA  [2][256] f32     @ 133120  2048    (codebooks L0, L3)
//   biasA  [3][128] f32     @ 135168  1536
//   red    [4][128] f32     @ 136704  2048
//   w3S    [128]    f32     @ 138752  512
#define SMEM_BYTES 139264
#define WTS (128 * 40)
#define WTB (3 * WTS)

__global__ __launch_bounds__(NT, 2)
void ecnr_fwd(const float* __restrict__ x,
              const int*   __restrict__ mlp_idx,
              const int*   __restrict__ block_idx,
              const float* __restrict__ latent,
              const float* __restrict__ cent0, const int* __restrict__ lab0, const float* __restrict__ bias0,
              const float* __restrict__ cent1, const int* __restrict__ lab1, const float* __restrict__ bias1,
              const float* __restrict__ cent2, const int* __restrict__ lab2, const float* __restrict__ bias2,
              const float* __restrict__ cent3, const int* __restrict__ lab3, const float* __restrict__ bias3,
              float* __restrict__ out)
{
    __shared__ __attribute__((aligned(16))) unsigned char smem[SMEM_BYTES];
    float   (*H)[132]  = (float(*)[132])(smem);
    __bf16*  WTb       = (__bf16*)(smem + 67584);
    float*   W0s       = (float*)(smem + 67584);
    float*   inT       = (float*)(smem + 75776);
    uint2*   centPak   = (uint2*)(smem + 129024);
    float*   centA     = (float*)(smem + 133120);
    float*   biasA     = (float*)(smem + 135168);
    float*   red       = (float*)(smem + 136704);
    float*   w3S       = (float*)(smem + 138752);

    const int t   = threadIdx.x;
    const int b   = blockIdx.x >> 4;
    const int p0  = (blockIdx.x & 15) * 128;
    const int mlp = mlp_idx[b];

    const int l   = t & 63;        // lane
    const int w   = t >> 6;        // wave 0..7
    const int q   = l >> 5;        // half-wave
    const int ln  = l & 31;
    const int pt  = w & 3;         // 32-row point tile
    const int ntb = (w >> 2) * 2;  // base of 2 owned 32-col channel tiles
    const int mrow = pt * 32 + ln;

    // ---------------- stage tables / input tile ----------------
    {
        // pre-split packed codebooks for layers 1,2
        const int li = t >> 8, k = t & 255;
        float c = (li ? cent2 : cent1)[k];
        unsigned u0, u1, u2;
        split3(c, u0, u1, u2);
        centPak[li * 256 + k] = make_uint2((u1 << 16) | u0, u2);
        // fp32 codebooks for layers 0,3
        centA[t] = (t < 256) ? cent0[t] : cent3[t - 256];
        // biases
        if (t < 128)       biasA[t] = bias0[mlp * 128 + t];
        else if (t < 256)  biasA[t] = bias1[mlp * 128 + (t - 128)];
        else if (t < 384)  biasA[t] = bias2[mlp * 128 + (t - 256)];
        // input tile: coords + latent broadcast, transposed [16][128]
        if (t < 128) {
            const float* xp = x + ((size_t)b * 2048 + p0 + t) * 3;
            inT[0 * 128 + t] = xp[0];
            inT[1 * 128 + t] = xp[1];
            inT[2 * 128 + t] = xp[2];
            const float* zp = latent + ((size_t)mlp * 8 + block_idx[b]) * 13;
            #pragma unroll
            for (int i = 0; i < 13; ++i) inT[(3 + i) * 128 + t] = zp[i];
        }
    }
    // prefetch layer-0 labels while tables settle
    const int4 l0v = ((const int4*)(lab0 + (size_t)mlp * 2048))[t];
    __syncthreads();

    // ---------------- dequant W0 (fp32) and w3 ----------------
    {
        const int k = t >> 5, n4 = (t & 31) * 4;
        float4 wv;
        wv.x = centA[l0v.x]; wv.y = centA[l0v.y];
        wv.z = centA[l0v.z]; wv.w = centA[l0v.w];
        *(float4*)&W0s[k * 128 + n4] = wv;
        if (t < 32) {
            const int4 lv = ((const int4*)(lab3 + (size_t)mlp * 128))[t];
            w3S[t * 4 + 0] = centA[256 + lv.x];
            w3S[t * 4 + 1] = centA[256 + lv.y];
            w3S[t * 4 + 2] = centA[256 + lv.z];
            w3S[t * 4 + 3] = centA[256 + lv.w];
        }
    }
    const int* labL[2] = {lab1 + (size_t)mlp * 16384, lab2 + (size_t)mlp * 16384};
    int lp[8];
    auto loadlabs = [&](const int* lb, int kp) {
        #pragma unroll
        for (int u = 0; u < 4; ++u) {
            const int wi  = u * NT + t;
            const int kp2 = wi & 15;
            const int n   = (wi >> 4) & 127;
            const int kg  = kp * 32 + 2 * kp2;
            lp[2 * u]     = lb[kg * 128 + n];
            lp[2 * u + 1] = lb[kg * 128 + 128 + n];
        }
    };
    loadlabs(labL[0], 0);
    __syncthreads();

    // ---------------- layer 0: [128x16]@[16x128] + bias, sin -> H ----------------
    {
        const int pb = (t & 31) * 4, cb = (t >> 5) * 8;
        float a0[4][8];
        #pragma unroll
        for (int p = 0; p < 4; ++p)
            #pragma unroll
            for (int j = 0; j < 8; ++j) a0[p][j] = biasA[cb + j];
        #pragma unroll
        for (int k = 0; k < 16; ++k) {
            const float4 hv = *(const float4*)&inT[k * 128 + pb];
            const float4 wa = *(const float4*)&W0s[k * 128 + cb];
            const float4 wb = *(const float4*)&W0s[k * 128 + cb + 4];
            const float h[4] = {hv.x, hv.y, hv.z, hv.w};
            const float wj[8] = {wa.x, wa.y, wa.z, wa.w, wb.x, wb.y, wb.z, wb.w};
            #pragma unroll
            for (int p = 0; p < 4; ++p)
                #pragma unroll
                for (int j = 0; j < 8; ++j)
                    a0[p][j] = __builtin_fmaf(h[p], wj[j], a0[p][j]);
        }
        #pragma unroll
        for (int p = 0; p < 4; ++p) {
            float4 va, vb;
            va.x = sin_omega(a0[p][0]); va.y = sin_omega(a0[p][1]);
            va.z = sin_omega(a0[p][2]); va.w = sin_omega(a0[p][3]);
            vb.x = sin_omega(a0[p][4]); vb.y = sin_omega(a0[p][5]);
            vb.z = sin_omega(a0[p][6]); vb.w = sin_omega(a0[p][7]);
            *(float4*)&H[pb + p][cb]     = va;
            *(float4*)&H[pb + p][cb + 4] = vb;
        }
    }
    __syncthreads();  // H ready; W0s/inT dead (WT dequant may overwrite)

    // ---------------- layers 1,2: bf16x3 MFMA ----------------
    #pragma unroll 1
    for (int L = 0; L < 2; ++L) {
        v16f acc0, acc1;
        {
            const float b0v = biasA[(L + 1) * 128 + ntb * 32 + ln];
            const float b1v = biasA[(L + 1) * 128 + (ntb + 1) * 32 + ln];
            #pragma unroll
            for (int r = 0; r < 16; ++r) { acc0[r] = b0v; acc1[r] = b1v; }
        }
        #pragma unroll 1
        for (int kp = 0; kp < 4; ++kp) {
            const int buf = kp & 1;
            // dequant panel kp into WT[buf] via packed-codebook gathers
            #pragma unroll
            for (int u = 0; u < 4; ++u) {
                const int wi  = u * NT + t;
                const int kp2 = wi & 15;
                const int n   = (wi >> 4) & 127;
                const uint2 g0 = centPak[L * 256 + lp[2 * u]];
                const uint2 g1 = centPak[L * 256 + lp[2 * u + 1]];
                const unsigned s0 = (g0.x & 0xffffu) | (g1.x << 16);
                const unsigned s1 = (g0.x >> 16)     | (g1.x & 0xffff0000u);
                const unsigned s2 = g0.y | (g1.y << 16);
                __bf16* base = WTb + buf * WTB + n * 40 + kp2 * 2;
                *(unsigned*)(base)           = s0;
                *(unsigned*)(base + WTS)     = s1;
                *(unsigned*)(base + 2 * WTS) = s2;
            }
            if (kp < 3) loadlabs(labL[L], kp + 1);
            else if (L == 0) loadlabs(labL[1], 0);
            __syncthreads();
            // MFMA over panel (2 chunks of K=16)
            #pragma unroll
            for (int kc = 0; kc < 2; ++kc) {
                const int kb = kp * 32 + kc * 16 + q * 8;
                float hf[8];
                *(float4*)&hf[0] = *(const float4*)&H[mrow][kb];
                *(float4*)&hf[4] = *(const float4*)&H[mrow][kb + 4];
                v8bf a0, a1, a2;
                #pragma unroll
                for (int j = 0; j < 8; ++j) {
                    const float c = hf[j];
                    const __bf16 b0 = (__bf16)c; const float r1 = c - (float)b0;
                    const __bf16 b1 = (__bf16)r1;
                    a0[j] = b0; a1[j] = b1; a2[j] = (__bf16)(r1 - (float)b1);
                }
                #pragma unroll
                for (int e = 0; e < 2; ++e) {
                    const __bf16* wp = WTb + buf * WTB + ((ntb + e) * 32 + ln) * 40 + kc * 16 + q * 8;
                    const v8bf bb0 = *(const v8bf*)(wp);
                    const v8bf bb1 = *(const v8bf*)(wp + WTS);
                    const v8bf bb2 = *(const v8bf*)(wp + 2 * WTS);
                    v16f a = e ? acc1 : acc0;
                    a = MFMA(a0, bb0, a);
                    a = MFMA(a0, bb1, a);
                    a = MFMA(a1, bb0, a);
                    a = MFMA(a0, bb2, a);
                    a = MFMA(a2, bb0, a);
                    a = MFMA(a1, bb1, a);
                    if (e) acc1 = a; else acc0 = a;
                }
            }
        }
        __syncthreads();  // all H reads for this layer done
        // epilogue: sin, write back to H (C/D layout: col=lane&31, row=(r&3)+8*(r>>2)+4*q)
        #pragma unroll
        for (int e = 0; e < 2; ++e) {
            const int n = (ntb + e) * 32 + ln;
            #pragma unroll
            for (int r = 0; r < 16; ++r) {
                const int m = pt * 32 + (r & 3) + 8 * (r >> 2) + 4 * q;
                const float v = e ? acc1[r] : acc0[r];
                H[m][n] = sin_omega(v);
            }
        }
        // next layer's panel-0 dequant + its sync orders these H writes
        // before any MFMA H read; WT[0] was last read at kp==2 (pre-sync).
    }
    __syncthreads();  // layer-2 H visible

    // ---------------- layer 3: [128x128]@[128x1] + bias ----------------
    {
        const int p = t & 127, qk = t >> 7;
        float s = 0.0f;
        #pragma unroll
        for (int i = 0; i < 8; ++i) {
            const float4 hv = *(const float4*)&H[p][qk * 32 + i * 4];
            s = __builtin_fmaf(hv.x, w3S[qk * 32 + i * 4 + 0], s);
            s = __builtin_fmaf(hv.y, w3S[qk * 32 + i * 4 + 1], s);
            s = __builtin_fmaf(hv.z, w3S[qk * 32 + i * 4 + 2], s);
            s = __builtin_fmaf(hv.w, w3S[qk * 32 + i * 4 + 3], s);
        }
        red[qk * 128 + p] = s;
    }
    __syncthreads();
    if (t < 128) {
        const float o = red[t] + red[128 + t] + red[256 + t] + red[384 + t] + bias3[mlp];
        out[(size_t)b * 2048 + p0 + t] = o;
    }
}

extern "C" void kernel_launch(void* const* d_in, const int* in_sizes, int n_in,
                              void* d_out, int out_size, void* d_ws, size_t ws_size,
                              hipStream_t stream) {
    (void)in_sizes; (void)n_in; (void)d_ws; (void)ws_size; (void)out_size;
    ecnr_fwd<<<4096, NT, 0, stream>>>(
        (const float*)d_in[0],  (const int*)d_in[1],  (const int*)d_in[2],
        (const float*)d_in[3],
        (const float*)d_in[4],  (const int*)d_in[5],  (const float*)d_in[6],
        (const float*)d_in[7],  (const int*)d_in[8],  (const float*)d_in[9],
        (const float*)d_in[10], (const int*)d_in[11], (const float*)d_in[12],
        (const float*)d_in[13], (const int*)d_in[14], (const float*)d_in[15],
        (float*)d_out);
}

// Round 4
// 329.743 us; speedup vs baseline: 1.7154x; 1.4314x over previous
//
#include <hip/hip_runtime.h>

// ECNR forward, R4: two kernels.
//  K1 (ecnr_dequant): dequantize all codebook weights once into d_ws as
//     packed bf16x2 (u32 = lo|hi split), pre-transposed [n][k], with k-chunk
//     XOR bank-swizzle baked into the global layout.
//  K2 (ecnr_fwd): 4096 blocks (= 16 tiles x 256 samples, sample-major so all
//     tiles of a sample share an XCD) x 1024 threads (16 waves, 4/SIMD).
//     All layers on v_mfma_f32_32x32x16_bf16 with bf16x2 split (3 products).
//     W staged LDS via global_load_lds DMA (no gathers in hot kernel).
//     H kept packed-u32 in LDS. 7 barriers/block. LDS 141 KB, 1 block/CU.

typedef unsigned int u32;
typedef __bf16 v8bf  __attribute__((ext_vector_type(8)));
typedef float  v16f  __attribute__((ext_vector_type(16)));
typedef u32    v4u   __attribute__((ext_vector_type(4)));

#define MFMA(a, b, c) __builtin_amdgcn_mfma_f32_32x32x16_bf16(a, b, c, 0, 0, 0)

// sin(30*pre): Cody-Waite 2-term reduction to [-pi,pi] + native sin (r1-proven).
__device__ __forceinline__ float sin_omega(float pre) {
    float x = 30.0f * pre;
    float k = __builtin_rintf(x * 0.15915494309189535f);
    float r = __builtin_fmaf(k, -6.2831854820251465f, x);
    r = __builtin_fmaf(k, 1.7484556e-07f, r);
    return __sinf(r);
}

// fp32 -> packed bf16x2 (lo = leading split, hi = residual split)
__device__ __forceinline__ u32 pack2(float c) {
    __bf16 b0 = (__bf16)c;
    float  f0 = (float)b0;
    __bf16 b1 = (__bf16)(c - f0);
    u32 u0 = (u32)__builtin_bit_cast(unsigned short, b0);
    u32 u1 = (u32)__builtin_bit_cast(unsigned short, b1);
    return u0 | (u1 << 16);
}

// packed bf16x2 -> fp32 (exact reconstruction of the two splits)
__device__ __forceinline__ float upk(u32 u) {
    return __builtin_bit_cast(float, u << 16) +
           __builtin_bit_cast(float, u & 0xffff0000u);
}

// 8 packed u32 (k ascending) -> two v8bf fragments (split0, split1)
__device__ __forceinline__ void unpack8(const u32* u, v8bf& a0, v8bf& a1) {
    v4u lo, hi;
    #pragma unroll
    for (int r = 0; r < 4; ++r) {
        lo[r] = (u[2 * r] & 0xffffu) | (u[2 * r + 1] << 16);
        hi[r] = (u[2 * r] >> 16)     | (u[2 * r + 1] & 0xffff0000u);
    }
    a0 = __builtin_bit_cast(v8bf, lo);
    a1 = __builtin_bit_cast(v8bf, hi);
}

// async global->LDS DMA, 16 B/lane; lds base must be wave-uniform (HW adds lane*16)
__device__ __forceinline__ void dma16(const u32* g, u32* l) {
    __builtin_amdgcn_global_load_lds(
        (const __attribute__((address_space(1))) u32*)g,
        (__attribute__((address_space(3))) u32*)l, 16, 0, 0);
}

// ---------------------------------------------------------------------------
// Kernel 1: dequant all 256 MLPs into d_ws.
// Layout per mlp:
//   wpk1/wpk2: [n=128][k=128] u32, element (n,k) at n*128 + ((k>>2)^(n&7))*4 + (k&3)
//   w0pk:      [n=128][k=16]  u32, element (n,k) at n*16  + ((k>>2)^((n>>1)&3))*4 + (k&3)
//   w3pk:      [k=128] u32 flat
// ---------------------------------------------------------------------------
__global__ __launch_bounds__(512)
void ecnr_dequant(const float* __restrict__ cent0, const int* __restrict__ lab0,
                  const float* __restrict__ cent1, const int* __restrict__ lab1,
                  const float* __restrict__ cent2, const int* __restrict__ lab2,
                  const float* __restrict__ cent3, const int* __restrict__ lab3,
                  u32* __restrict__ wpk1, u32* __restrict__ wpk2,
                  u32* __restrict__ w0pk, u32* __restrict__ w3pk)
{
    __shared__ u32 cpk[4][256];      // packed codebooks: L1, L2, L0, L3
    __shared__ u32 stage[128 * 33];  // padded staging
    const int t = threadIdx.x;
    const int m = blockIdx.x;

    if (t < 256) { cpk[0][t] = pack2(cent1[t]); cpk[1][t] = pack2(cent2[t]); }
    else { int k = t - 256; cpk[2][k] = pack2(cent0[k]); cpk[3][k] = pack2(cent3[k]); }
    __syncthreads();

    // layers 1, 2: [k=128][n=128] labels -> swizzled [n][k]
    for (int L = 0; L < 2; ++L) {
        const int* lab = (L ? lab2 : lab1) + (size_t)m * 16384;
        u32* outp      = (L ? wpk2 : wpk1) + (size_t)m * 16384;
        for (int nt = 0; nt < 4; ++nt) {
            #pragma unroll
            for (int i = 0; i < 8; ++i) {
                int idx = i * 512 + t;              // 4096 = 128k x 32n
                int n = idx & 31, k = idx >> 5;
                int lb = lab[k * 128 + nt * 32 + n];
                stage[k * 33 + n] = cpk[L][lb];
            }
            __syncthreads();
            #pragma unroll
            for (int np = 0; np < 2; ++np) {
                int c = t & 31, n = np * 16 + (t >> 5);
                int cs = c ^ (n & 7);               // source chunk for position c
                v4u v;
                v[0] = stage[(4 * cs + 0) * 33 + n];
                v[1] = stage[(4 * cs + 1) * 33 + n];
                v[2] = stage[(4 * cs + 2) * 33 + n];
                v[3] = stage[(4 * cs + 3) * 33 + n];
                *(v4u*)(outp + (nt * 32 + n) * 128 + (c << 2)) = v;
            }
            __syncthreads();
        }
    }
    // layer 0: [k=16][n=128]
    {
        const int* lab = lab0 + (size_t)m * 2048;
        #pragma unroll
        for (int i = 0; i < 4; ++i) {
            int idx = i * 512 + t;
            int n = idx & 127, k = idx >> 7;
            stage[k * 129 + n] = cpk[2][lab[idx]];
        }
        __syncthreads();
        {
            int n = t >> 2, c = t & 3;
            int cs = c ^ ((n >> 1) & 3);
            v4u v;
            v[0] = stage[(4 * cs + 0) * 129 + n];
            v[1] = stage[(4 * cs + 1) * 129 + n];
            v[2] = stage[(4 * cs + 2) * 129 + n];
            v[3] = stage[(4 * cs + 3) * 129 + n];
            *(v4u*)(w0pk + (size_t)m * 2048 + n * 16 + (c << 2)) = v;
        }
    }
    // layer 3
    if (t < 128) w3pk[(size_t)m * 128 + t] = cpk[3][lab3[(size_t)m * 128 + t]];
}

// ---------------------------------------------------------------------------
// Kernel 2: fused forward. LDS: Hs 67,584 + WTs 65,536 + W0s/red 8,192 + zpk 64
// ---------------------------------------------------------------------------
__global__ __launch_bounds__(1024, 4)
void ecnr_fwd(const float* __restrict__ x,
              const int*   __restrict__ mlp_idx,
              const int*   __restrict__ block_idx,
              const float* __restrict__ latent,
              const float* __restrict__ bias0, const float* __restrict__ bias1,
              const float* __restrict__ bias2, const float* __restrict__ bias3,
              const u32* __restrict__ wpk1, const u32* __restrict__ wpk2,
              const u32* __restrict__ w0pk, const u32* __restrict__ w3pk,
              float* __restrict__ out)
{
    __shared__ __attribute__((aligned(16))) u32 Hs[128 * 132];   // packed H, [m][k], stride 132
    __shared__ __attribute__((aligned(16))) u32 WTs[128 * 128];  // DMA'd swizzled W panel
    __shared__ __attribute__((aligned(16))) u32 W0s[16 * 128];   // W0 panel; reused as red[8][128] f32
    __shared__ __attribute__((aligned(16))) u32 zpk[16];

    const int t  = threadIdx.x;
    const int b  = blockIdx.x & 255;       // sample-major: all 16 tiles of b -> same XCD
    const int p0 = (blockIdx.x >> 8) * 128;
    const int m  = mlp_idx[b];

    const int l  = t & 63, w = t >> 6;     // lane, wave 0..15
    const int q  = l >> 5, ln = l & 31;
    const int pt = w & 3, nt = w >> 2;     // 4x4 grid of 32x32 tiles, 1 tile/wave
    const int mrow = pt * 32 + ln;         // A row
    const int nn   = nt * 32 + ln;         // B/C col
    const int sw   = nn & 7;

    // ---- S0: DMA W0 + WT(L1); stage z; load x, biases ----
    if (w < 8) dma16(w0pk + (size_t)m * 2048 + w * 256 + l * 4, W0s + w * 256);
    {
        const u32* g = wpk1 + (size_t)m * 16384;
        #pragma unroll
        for (int i = 0; i < 4; ++i) {
            int cid = w * 4 + i;
            dma16(g + cid * 256 + l * 4, WTs + cid * 256);
        }
    }
    if (t < 13) {
        int zb = block_idx[b];
        zpk[t] = pack2(latent[((size_t)m * 8 + zb) * 13 + t]);
    }
    float x0v = 0.f, x1v = 0.f, x2v = 0.f;
    {
        const float* xp = x + (size_t)(b * 2048 + p0 + mrow) * 3;
        if (q == 0) { x0v = xp[0]; x1v = xp[1]; x2v = xp[2]; }
    }
    const float bias0v = bias0[m * 128 + nn];
    const float bias1v = bias1[m * 128 + nn];
    const float bias2v = bias2[m * 128 + nn];
    __syncthreads();  // B1: DMAs drained, zpk visible

    // ---- S1: layer 0 (A in registers, B = W0s), epi -> Hs ----
    {
        u32 ua[8];
        if (q == 0) {
            ua[0] = pack2(x0v); ua[1] = pack2(x1v); ua[2] = pack2(x2v);
            #pragma unroll
            for (int j = 0; j < 5; ++j) ua[3 + j] = zpk[j];
        } else {
            #pragma unroll
            for (int j = 0; j < 8; ++j) ua[j] = zpk[5 + j];
        }
        v8bf a0, a1, b0v, b1v;
        unpack8(ua, a0, a1);
        u32 ub[8];
        const int sw0 = (nn >> 1) & 3;
        const int c0 = 2 * q;
        *(v4u*)&ub[0] = *(const v4u*)&W0s[nn * 16 + ((c0 ^ sw0) << 2)];
        *(v4u*)&ub[4] = *(const v4u*)&W0s[nn * 16 + (((c0 + 1) ^ sw0) << 2)];
        unpack8(ub, b0v, b1v);
        v16f acc;
        #pragma unroll
        for (int r = 0; r < 16; ++r) acc[r] = bias0v;
        acc = MFMA(a0, b0v, acc);
        acc = MFMA(a1, b0v, acc);
        acc = MFMA(a0, b1v, acc);
        #pragma unroll
        for (int r = 0; r < 16; ++r) {
            const int mm = pt * 32 + (r & 3) + 8 * (r >> 2) + 4 * q;
            Hs[mm * 132 + nn] = pack2(sin_omega(acc[r]));
        }
    }
    __syncthreads();  // B2: H(L0) visible

    // ---- layers 1, 2 ----
    #pragma unroll 1
    for (int L = 0; L < 2; ++L) {
        const float bv = L ? bias2v : bias1v;
        v16f acc;
        #pragma unroll
        for (int r = 0; r < 16; ++r) acc[r] = bv;
        #pragma unroll
        for (int kc = 0; kc < 8; ++kc) {
            u32 ua[8], ub[8];
            const u32* hp = &Hs[mrow * 132 + kc * 16 + q * 8];
            *(v4u*)&ua[0] = *(const v4u*)hp;
            *(v4u*)&ua[4] = *(const v4u*)(hp + 4);
            const int c0 = kc * 4 + 2 * q;
            *(v4u*)&ub[0] = *(const v4u*)&WTs[nn * 128 + ((c0 ^ sw) << 2)];
            *(v4u*)&ub[4] = *(const v4u*)&WTs[nn * 128 + (((c0 + 1) ^ sw) << 2)];
            v8bf a0, a1, b0v, b1v;
            unpack8(ua, a0, a1);
            unpack8(ub, b0v, b1v);
            acc = MFMA(a0, b0v, acc);
            acc = MFMA(a1, b0v, acc);
            acc = MFMA(a0, b1v, acc);
        }
        __syncthreads();  // B3/B5: all H & WT reads of this layer done
        if (L == 0) {     // prefetch W(L2) into WTs (drained at B4)
            const u32* g = wpk2 + (size_t)m * 16384;
            #pragma unroll
            for (int i = 0; i < 4; ++i) {
                int cid = w * 4 + i;
                dma16(g + cid * 256 + l * 4, WTs + cid * 256);
            }
        }
        #pragma unroll
        for (int r = 0; r < 16; ++r) {
            const int mm = pt * 32 + (r & 3) + 8 * (r >> 2) + 4 * q;
            Hs[mm * 132 + nn] = pack2(sin_omega(acc[r]));
        }
        __syncthreads();  // B4/B6: DMA drained + H(L) visible
    }

    // ---- S6: layer 3 partials (8-way k-split) ----
    {
        const int p = t & 127, qk = t >> 7;
        u32 uh[16], uw[16];
        const u32* hp = &Hs[p * 132 + qk * 16];
        #pragma unroll
        for (int i = 0; i < 4; ++i) *(v4u*)&uh[4 * i] = *(const v4u*)(hp + 4 * i);
        const u32* wp = w3pk + (size_t)m * 128 + qk * 16;
        #pragma unroll
        for (int i = 0; i < 4; ++i) *(v4u*)&uw[4 * i] = *(const v4u*)(wp + 4 * i);
        float s = 0.f;
        #pragma unroll
        for (int i = 0; i < 16; ++i) s = __builtin_fmaf(upk(uh[i]), upk(uw[i]), s);
        ((float*)W0s)[qk * 128 + p] = s;
    }
    __syncthreads();  // B7

    if (t < 128) {
        const float* red = (const float*)W0s;
        float o = bias3[m];
        #pragma unroll
        for (int qk = 0; qk < 8; ++qk) o += red[qk * 128 + t];
        out[(size_t)b * 2048 + p0 + t] = o;
    }
}

extern "C" void kernel_launch(void* const* d_in, const int* in_sizes, int n_in,
                              void* d_out, int out_size, void* d_ws, size_t ws_size,
                              hipStream_t stream) {
    (void)in_sizes; (void)n_in; (void)out_size; (void)ws_size;
    u32* wpk1 = (u32*)d_ws;                  // 256*16384 u32
    u32* wpk2 = wpk1 + 256 * 16384;          // 256*16384 u32
    u32* w0pk = wpk2 + 256 * 16384;          // 256*2048 u32
    u32* w3pk = w0pk + 256 * 2048;           // 256*128 u32   (total ~35.8 MB)

    ecnr_dequant<<<256, 512, 0, stream>>>(
        (const float*)d_in[4],  (const int*)d_in[5],
        (const float*)d_in[7],  (const int*)d_in[8],
        (const float*)d_in[10], (const int*)d_in[11],
        (const float*)d_in[13], (const int*)d_in[14],
        wpk1, wpk2, w0pk, w3pk);

    ecnr_fwd<<<4096, 1024, 0, stream>>>(
        (const float*)d_in[0], (const int*)d_in[1], (const int*)d_in[2],
        (const float*)d_in[3],
        (const float*)d_in[6], (const float*)d_in[9],
        (const float*)d_in[12], (const float*)d_in[15],
        wpk1, wpk2, w0pk, w3pk,
        (float*)d_out);
}

// Round 5
// 296.394 us; speedup vs baseline: 1.9084x; 1.1125x over previous
//
#include <hip/hip_runtime.h>

// ECNR forward, R5.
//  K1 ecnr_dequant: 2304 blocks (= 256 mlp x {8 W-panels + w0/w3}), 256 thr.
//     W (layers 1,2) written as TWO pre-split bf16 planes (lo, hi) per layer,
//     [n=128][k=128], 16B-chunk XOR-swizzle (chunk ^ (n&15)) baked in.
//  K2 ecnr_fwd: 4096 blocks x 1024 thr (16 waves, 1 block/CU, 141 KB LDS).
//     Layers 1,2: v_mfma_f32_32x32x16_bf16, bf16x2 split, FULL 4 products.
//     B fragments: direct ds_read_b128 from pre-split planes (no unpack).
//     A fragments: packed-u32 H + v_perm_b32 unpack (8 ops).
//     sin(30x) via v_sin_f32(fract(x*30/2pi)).

typedef unsigned int u32;
typedef unsigned short u16;
typedef __bf16 v8bf  __attribute__((ext_vector_type(8)));
typedef float  v16f  __attribute__((ext_vector_type(16)));
typedef u32    v4u   __attribute__((ext_vector_type(4)));

#define MFMA(a, b, c) __builtin_amdgcn_mfma_f32_32x32x16_bf16(a, b, c, 0, 0, 0)

// sin(30*pre) = v_sin(fract(pre * 30/2pi)); v_sin takes revolutions.
__device__ __forceinline__ float sin_omega(float pre) {
    float rev = pre * 4.774648292756860f;     // 30/(2*pi)
    rev -= __builtin_floorf(rev);             // exact fract -> [0,1)
    return __builtin_amdgcn_sinf(rev);
}

// fp32 -> packed bf16x2 (low16 = leading split, high16 = residual)
__device__ __forceinline__ u32 pack2(float c) {
    __bf16 b0 = (__bf16)c;
    float  f0 = (float)b0;
    __bf16 b1 = (__bf16)(c - f0);
    return (u32)__builtin_bit_cast(u16, b0) |
           ((u32)__builtin_bit_cast(u16, b1) << 16);
}

__device__ __forceinline__ float upk(u32 u) {
    return __builtin_bit_cast(float, u << 16) +
           __builtin_bit_cast(float, u & 0xffff0000u);
}

// two v4u of packed bf16x2 (k ascending) -> split fragments via v_perm_b32
__device__ __forceinline__ void unpack8p(v4u A, v4u B, v8bf& a0, v8bf& a1) {
    v4u lo, hi;
    lo[0] = __builtin_amdgcn_perm(A[1], A[0], 0x05040100u);
    lo[1] = __builtin_amdgcn_perm(A[3], A[2], 0x05040100u);
    lo[2] = __builtin_amdgcn_perm(B[1], B[0], 0x05040100u);
    lo[3] = __builtin_amdgcn_perm(B[3], B[2], 0x05040100u);
    hi[0] = __builtin_amdgcn_perm(A[1], A[0], 0x07060302u);
    hi[1] = __builtin_amdgcn_perm(A[3], A[2], 0x07060302u);
    hi[2] = __builtin_amdgcn_perm(B[1], B[0], 0x07060302u);
    hi[3] = __builtin_amdgcn_perm(B[3], B[2], 0x07060302u);
    a0 = __builtin_bit_cast(v8bf, lo);
    a1 = __builtin_bit_cast(v8bf, hi);
}

// async global->LDS DMA, 16 B/lane (lane's own gaddr; LDS dest uniform+lane*16)
__device__ __forceinline__ void dma16(const u32* g, u32* l) {
    __builtin_amdgcn_global_load_lds(
        (const __attribute__((address_space(1))) u32*)g,
        (__attribute__((address_space(3))) u32*)l, 16, 0, 0);
}

// ---------------------------------------------------------------------------
// K1: dequant. blockIdx = m*9 + j. j<8: (L=j>>2, nt=j&3) one 32n x 128k panel
// of layer L -> lo/hi bf16 planes. j==8: w0 (packed-u32, swizzled) + w3 (f32).
// Plane layout per mlp (u16 units): lo[16384] then hi[16384]; element (n,k) at
// n*128 + ((k>>3)^(n&15))*8 + (k&7).
// ---------------------------------------------------------------------------
__global__ __launch_bounds__(256)
void ecnr_dequant(const float* __restrict__ cent0, const int* __restrict__ lab0,
                  const float* __restrict__ cent1, const int* __restrict__ lab1,
                  const float* __restrict__ cent2, const int* __restrict__ lab2,
                  const float* __restrict__ cent3, const int* __restrict__ lab3,
                  u16* __restrict__ wpl1, u16* __restrict__ wpl2,
                  u32* __restrict__ w0pk, float* __restrict__ w3f)
{
    __shared__ u32 cpk[256];
    __shared__ u32 stage[128 * 33];
    const int t = threadIdx.x;
    const int m = blockIdx.x / 9;
    const int j = blockIdx.x - m * 9;

    if (j < 8) {
        const int L  = j >> 2;
        const int nt = j & 3;
        cpk[t] = pack2((L ? cent2 : cent1)[t]);
        __syncthreads();
        const int* lab = (L ? lab2 : lab1) + (size_t)m * 16384;
        #pragma unroll
        for (int i = 0; i < 16; ++i) {
            const int idx = i * 256 + t;
            const int n = idx & 31, k = idx >> 5;
            stage[k * 33 + n] = cpk[lab[k * 128 + nt * 32 + n]];
        }
        __syncthreads();
        u16* base = (L ? wpl2 : wpl1) + (size_t)m * 32768;
        const int n  = t >> 3;
        const int ng = nt * 32 + n;
        #pragma unroll
        for (int s = 0; s < 2; ++s) {
            const int cpos = (t & 7) + s * 8;
            const int csrc = cpos ^ (ng & 15);
            u32 u[8];
            #pragma unroll
            for (int jj = 0; jj < 8; ++jj) u[jj] = stage[(8 * csrc + jj) * 33 + n];
            v4u lo, hi;
            #pragma unroll
            for (int r = 0; r < 4; ++r) {
                lo[r] = __builtin_amdgcn_perm(u[2*r+1], u[2*r], 0x05040100u);
                hi[r] = __builtin_amdgcn_perm(u[2*r+1], u[2*r], 0x07060302u);
            }
            *(v4u*)(base + ng * 128 + cpos * 8)         = lo;
            *(v4u*)(base + 16384 + ng * 128 + cpos * 8) = hi;
        }
    } else {
        cpk[t] = pack2(cent0[t]);
        __syncthreads();
        const int* lab = lab0 + (size_t)m * 2048;
        #pragma unroll
        for (int i = 0; i < 8; ++i) {
            const int idx = i * 256 + t;
            const int n = idx & 127, k = idx >> 7;
            stage[k * 129 + n] = cpk[lab[idx]];
        }
        __syncthreads();
        #pragma unroll
        for (int s = 0; s < 2; ++s) {
            const int tt = s * 256 + t;
            const int n = tt >> 2, c = tt & 3;
            const int cs = c ^ ((n >> 1) & 3);
            v4u v;
            #pragma unroll
            for (int jj = 0; jj < 4; ++jj) v[jj] = stage[(4 * cs + jj) * 129 + n];
            *(v4u*)(w0pk + (size_t)m * 2048 + n * 16 + 4 * c) = v;
        }
        if (t < 128) w3f[(size_t)m * 128 + t] = cent3[lab3[(size_t)m * 128 + t]];
    }
}

// ---------------------------------------------------------------------------
// K2: fused forward.
// LDS: Hs 67,584 + WTs 65,536 + W0s/red 8,192 + zpk 64 = 141,376 B
// ---------------------------------------------------------------------------
__global__ __launch_bounds__(1024, 4)
void ecnr_fwd(const float* __restrict__ x,
              const int*   __restrict__ mlp_idx,
              const int*   __restrict__ block_idx,
              const float* __restrict__ latent,
              const float* __restrict__ bias0, const float* __restrict__ bias1,
              const float* __restrict__ bias2, const float* __restrict__ bias3,
              const u16* __restrict__ wpl1, const u16* __restrict__ wpl2,
              const u32* __restrict__ w0pk, const float* __restrict__ w3f,
              float* __restrict__ out)
{
    __shared__ __attribute__((aligned(16))) u32 Hs[128 * 132]; // packed H [m][k]
    __shared__ __attribute__((aligned(16))) u16 WTs[32768];    // lo plane | hi plane
    __shared__ __attribute__((aligned(16))) u32 W0s[16 * 128]; // packed W0; reused as red
    __shared__ __attribute__((aligned(16))) u32 zpk[16];

    const int t  = threadIdx.x;
    const int b  = blockIdx.x & 255;
    const int p0 = (blockIdx.x >> 8) * 128;
    const int m  = mlp_idx[b];

    const int l  = t & 63, w = t >> 6;
    const int q  = l >> 5, ln = l & 31;
    const int pt = w & 3, nt = w >> 2;
    const int mrow = pt * 32 + ln;
    const int nn   = nt * 32 + ln;
    const int sw   = nn & 15;

    // ---- S0: DMA W0 + W(L1); stage z; load x, biases ----
    if (w < 8) dma16(w0pk + (size_t)m * 2048 + w * 256 + l * 4, W0s + w * 256);
    {
        const u32* g = (const u32*)(wpl1 + (size_t)m * 32768);
        #pragma unroll
        for (int i = 0; i < 4; ++i) {
            const int cid = w * 4 + i;
            dma16(g + cid * 256 + l * 4, (u32*)WTs + cid * 256);
        }
    }
    if (t < 13) {
        const int zb = block_idx[b];
        zpk[t] = pack2(latent[((size_t)m * 8 + zb) * 13 + t]);
    }
    float x0v = 0.f, x1v = 0.f, x2v = 0.f;
    {
        const float* xp = x + (size_t)(b * 2048 + p0 + mrow) * 3;
        if (q == 0) { x0v = xp[0]; x1v = xp[1]; x2v = xp[2]; }
    }
    const float bias0v = bias0[m * 128 + nn];
    const float bias1v = bias1[m * 128 + nn];
    const float bias2v = bias2[m * 128 + nn];
    __syncthreads();  // B1: DMAs drained, zpk visible

    // ---- S1: layer 0 (A in registers, B = packed W0s), epi -> Hs ----
    {
        v4u uA, uB;
        if (q == 0) {
            uA[0] = pack2(x0v); uA[1] = pack2(x1v); uA[2] = pack2(x2v); uA[3] = zpk[0];
            #pragma unroll
            for (int jj = 0; jj < 4; ++jj) uB[jj] = zpk[1 + jj];
        } else {
            #pragma unroll
            for (int jj = 0; jj < 4; ++jj) { uA[jj] = zpk[5 + jj]; uB[jj] = zpk[9 + jj]; }
        }
        v8bf a0, a1, b0v, b1v;
        unpack8p(uA, uB, a0, a1);
        const int sw0 = (nn >> 1) & 3;
        const int c0 = 2 * q;
        const v4u ubA = *(const v4u*)&W0s[nn * 16 + ((c0 ^ sw0) << 2)];
        const v4u ubB = *(const v4u*)&W0s[nn * 16 + (((c0 + 1) ^ sw0) << 2)];
        unpack8p(ubA, ubB, b0v, b1v);
        v16f acc;
        #pragma unroll
        for (int r = 0; r < 16; ++r) acc[r] = bias0v;
        acc = MFMA(a0, b0v, acc);
        acc = MFMA(a1, b0v, acc);
        acc = MFMA(a0, b1v, acc);
        acc = MFMA(a1, b1v, acc);
        #pragma unroll
        for (int r = 0; r < 16; ++r) {
            const int mm = pt * 32 + (r & 3) + 8 * (r >> 2) + 4 * q;
            Hs[mm * 132 + nn] = pack2(sin_omega(acc[r]));
        }
    }
    __syncthreads();  // B2: H(L0) visible

    // ---- layers 1, 2: bf16x2 MFMA, 4 products ----
    #pragma unroll 1
    for (int L = 0; L < 2; ++L) {
        const float bv = L ? bias2v : bias1v;
        v16f acc;
        #pragma unroll
        for (int r = 0; r < 16; ++r) acc[r] = bv;
        #pragma unroll
        for (int kc = 0; kc < 8; ++kc) {
            const u32* hp = &Hs[mrow * 132 + (kc << 4) + (q << 3)];
            const v4u uA = *(const v4u*)hp;
            const v4u uB = *(const v4u*)(hp + 4);
            v8bf a0, a1;
            unpack8p(uA, uB, a0, a1);
            const int pos = ((kc << 1) | q) ^ sw;
            const u16* wl = WTs + nn * 128 + pos * 8;
            const v8bf b0v = *(const v8bf*)wl;
            const v8bf b1v = *(const v8bf*)(wl + 16384);
            acc = MFMA(a0, b0v, acc);
            acc = MFMA(a1, b0v, acc);
            acc = MFMA(a0, b1v, acc);
            acc = MFMA(a1, b1v, acc);
        }
        __syncthreads();  // B3/B5: all H & WT reads of this layer done
        if (L == 0) {     // prefetch W(L2); drained at B4
            const u32* g = (const u32*)(wpl2 + (size_t)m * 32768);
            #pragma unroll
            for (int i = 0; i < 4; ++i) {
                const int cid = w * 4 + i;
                dma16(g + cid * 256 + l * 4, (u32*)WTs + cid * 256);
            }
        }
        #pragma unroll
        for (int r = 0; r < 16; ++r) {
            const int mm = pt * 32 + (r & 3) + 8 * (r >> 2) + 4 * q;
            Hs[mm * 132 + nn] = pack2(sin_omega(acc[r]));
        }
        __syncthreads();  // B4/B6: DMA drained + H(L) visible
    }

    // ---- layer 3: [128x128]@[128x1] + bias (8-way k-split) ----
    {
        const int p = t & 127, qk = t >> 7;
        const u32* hp = &Hs[p * 132 + qk * 16];
        const float* wq = w3f + (size_t)m * 128 + qk * 16;
        float s = 0.f;
        #pragma unroll
        for (int i = 0; i < 4; ++i) {
            const v4u uh = *(const v4u*)(hp + 4 * i);
            s = __builtin_fmaf(upk(uh[0]), wq[4 * i + 0], s);
            s = __builtin_fmaf(upk(uh[1]), wq[4 * i + 1], s);
            s = __builtin_fmaf(upk(uh[2]), wq[4 * i + 2], s);
            s = __builtin_fmaf(upk(uh[3]), wq[4 * i + 3], s);
        }
        ((float*)W0s)[qk * 128 + p] = s;
    }
    __syncthreads();  // B7

    if (t < 128) {
        const float* red = (const float*)W0s;
        float o = bias3[m];
        #pragma unroll
        for (int qk = 0; qk < 8; ++qk) o += red[qk * 128 + t];
        out[(size_t)b * 2048 + p0 + t] = o;
    }
}

extern "C" void kernel_launch(void* const* d_in, const int* in_sizes, int n_in,
                              void* d_out, int out_size, void* d_ws, size_t ws_size,
                              hipStream_t stream) {
    (void)in_sizes; (void)n_in; (void)out_size; (void)ws_size;
    u16*   wpl1 = (u16*)d_ws;                       // 256*32768 u16 = 16 MB
    u16*   wpl2 = wpl1 + (size_t)256 * 32768;       // 16 MB
    u32*   w0pk = (u32*)(wpl2 + (size_t)256 * 32768); // 2 MB
    float* w3f  = (float*)(w0pk + 256 * 2048);      // 128 KB  (total ~34.1 MB)

    ecnr_dequant<<<2304, 256, 0, stream>>>(
        (const float*)d_in[4],  (const int*)d_in[5],
        (const float*)d_in[7],  (const int*)d_in[8],
        (const float*)d_in[10], (const int*)d_in[11],
        (const float*)d_in[13], (const int*)d_in[14],
        wpl1, wpl2, w0pk, w3f);

    ecnr_fwd<<<4096, 1024, 0, stream>>>(
        (const float*)d_in[0], (const int*)d_in[1], (const int*)d_in[2],
        (const float*)d_in[3],
        (const float*)d_in[6], (const float*)d_in[9],
        (const float*)d_in[12], (const float*)d_in[15],
        wpl1, wpl2, w0pk, w3f,
        (float*)d_out);
}

// Round 6
// 294.010 us; speedup vs baseline: 1.9238x; 1.0081x over previous
//
#include <hip/hip_runtime.h>

// ECNR forward, R6.
//  K1 ecnr_dequant: 2304 blocks. W (L1,L2) -> two pre-split bf16 planes
//     (lo,hi) per layer in CHUNK-MAJOR layout: [16 k-chunks][128 n][8 k],
//     so fwd B-reads are base + (kc*2+q)*2048B with zero address math and
//     zero bank conflicts. W0 likewise ([2 chunks][128][8]), w3 as f32.
//  K2 ecnr_fwd: 4096 blocks x 1024 thr (16 waves, 1 block/CU, 130 KB LDS).
//     bf16x2 split MFMA (4 products). L0 A and B entirely in registers.
//     All hot LDS reads are one base VGPR + 16-bit immediate offset.
//     6 barriers; both W DMAs issued under compute (L0 / L1-epilogue).

typedef unsigned int u32;
typedef unsigned short u16;
typedef __bf16 v8bf  __attribute__((ext_vector_type(8)));
typedef float  v16f  __attribute__((ext_vector_type(16)));
typedef u32    v4u   __attribute__((ext_vector_type(4)));

#define MFMA(a, b, c) __builtin_amdgcn_mfma_f32_32x32x16_bf16(a, b, c, 0, 0, 0)

// sin(30*pre) = v_sin(fract(pre * 30/2pi)); v_sin takes revolutions.
__device__ __forceinline__ float sin_omega(float pre) {
    float rev = pre * 4.774648292756860f;     // 30/(2*pi)
    rev -= __builtin_floorf(rev);             // fract -> [0,1)
    return __builtin_amdgcn_sinf(rev);
}

// fp32 -> packed bf16x2 (low16 = leading split, high16 = residual)
__device__ __forceinline__ u32 pack2(float c) {
    __bf16 b0 = (__bf16)c;
    float  f0 = (float)b0;
    __bf16 b1 = (__bf16)(c - f0);
    return (u32)__builtin_bit_cast(u16, b0) |
           ((u32)__builtin_bit_cast(u16, b1) << 16);
}

__device__ __forceinline__ float upk(u32 u) {
    return __builtin_bit_cast(float, u << 16) +
           __builtin_bit_cast(float, u & 0xffff0000u);
}

// two v4u of packed bf16x2 (k ascending) -> split fragments via v_perm_b32
__device__ __forceinline__ void unpack8p(v4u A, v4u B, v8bf& a0, v8bf& a1) {
    v4u lo, hi;
    lo[0] = __builtin_amdgcn_perm(A[1], A[0], 0x05040100u);
    lo[1] = __builtin_amdgcn_perm(A[3], A[2], 0x05040100u);
    lo[2] = __builtin_amdgcn_perm(B[1], B[0], 0x05040100u);
    lo[3] = __builtin_amdgcn_perm(B[3], B[2], 0x05040100u);
    hi[0] = __builtin_amdgcn_perm(A[1], A[0], 0x07060302u);
    hi[1] = __builtin_amdgcn_perm(A[3], A[2], 0x07060302u);
    hi[2] = __builtin_amdgcn_perm(B[1], B[0], 0x07060302u);
    hi[3] = __builtin_amdgcn_perm(B[3], B[2], 0x07060302u);
    a0 = __builtin_bit_cast(v8bf, lo);
    a1 = __builtin_bit_cast(v8bf, hi);
}

// async global->LDS DMA, 16 B/lane
__device__ __forceinline__ void dma16(const u32* g, u32* l) {
    __builtin_amdgcn_global_load_lds(
        (const __attribute__((address_space(1))) u32*)g,
        (__attribute__((address_space(3))) u32*)l, 16, 0, 0);
}

// ---------------------------------------------------------------------------
// K1: dequant. blockIdx = m*9 + j. j<8: (L=j>>2, nt=j&3) one 32n x 128k panel.
// Plane layout per mlp (u16): lo[16384] | hi[16384]; element (n,k) at
// (k>>3)*1024 + n*8 + (k&7).
// ---------------------------------------------------------------------------
__global__ __launch_bounds__(256)
void ecnr_dequant(const float* __restrict__ cent0, const int* __restrict__ lab0,
                  const float* __restrict__ cent1, const int* __restrict__ lab1,
                  const float* __restrict__ cent2, const int* __restrict__ lab2,
                  const float* __restrict__ cent3, const int* __restrict__ lab3,
                  u16* __restrict__ wpl1, u16* __restrict__ wpl2,
                  u16* __restrict__ w0pl, float* __restrict__ w3f)
{
    __shared__ u32 cpk[256];
    __shared__ u32 stage[128 * 33];
    const int t = threadIdx.x;
    const int m = blockIdx.x / 9;
    const int j = blockIdx.x - m * 9;

    if (j < 8) {
        const int L  = j >> 2;
        const int nt = j & 3;
        cpk[t] = pack2((L ? cent2 : cent1)[t]);
        __syncthreads();
        const int* lab = (L ? lab2 : lab1) + (size_t)m * 16384;
        #pragma unroll
        for (int i = 0; i < 16; ++i) {
            const int idx = i * 256 + t;
            const int n = idx & 31, k = idx >> 5;
            stage[k * 33 + n] = cpk[lab[k * 128 + nt * 32 + n]];
        }
        __syncthreads();
        u16* base = (L ? wpl2 : wpl1) + (size_t)m * 32768;
        const int n  = t & 31;
        const int ng = nt * 32 + n;
        #pragma unroll
        for (int s = 0; s < 2; ++s) {
            const int c = (t >> 5) + 8 * s;
            u32 u[8];
            #pragma unroll
            for (int jj = 0; jj < 8; ++jj) u[jj] = stage[(8 * c + jj) * 33 + n];
            v4u lo, hi;
            #pragma unroll
            for (int r = 0; r < 4; ++r) {
                lo[r] = __builtin_amdgcn_perm(u[2*r+1], u[2*r], 0x05040100u);
                hi[r] = __builtin_amdgcn_perm(u[2*r+1], u[2*r], 0x07060302u);
            }
            *(v4u*)(base + c * 1024 + ng * 8)         = lo;
            *(v4u*)(base + 16384 + c * 1024 + ng * 8) = hi;
        }
    } else {
        cpk[t] = pack2(cent0[t]);
        __syncthreads();
        const int* lab = lab0 + (size_t)m * 2048;
        #pragma unroll
        for (int i = 0; i < 8; ++i) {
            const int idx = i * 256 + t;
            const int n = idx & 127, k = idx >> 7;
            stage[k * 129 + n] = cpk[lab[idx]];
        }
        __syncthreads();
        {
            const int c = t >> 7, n = t & 127;   // [2 chunks][128 n]
            u32 u[8];
            #pragma unroll
            for (int jj = 0; jj < 8; ++jj) u[jj] = stage[(8 * c + jj) * 129 + n];
            v4u lo, hi;
            #pragma unroll
            for (int r = 0; r < 4; ++r) {
                lo[r] = __builtin_amdgcn_perm(u[2*r+1], u[2*r], 0x05040100u);
                hi[r] = __builtin_amdgcn_perm(u[2*r+1], u[2*r], 0x07060302u);
            }
            u16* b0 = w0pl + (size_t)m * 4096;
            *(v4u*)(b0 + c * 1024 + n * 8)        = lo;
            *(v4u*)(b0 + 2048 + c * 1024 + n * 8) = hi;
        }
        if (t < 128) w3f[(size_t)m * 128 + t] = cent3[lab3[(size_t)m * 128 + t]];
    }
}

// ---------------------------------------------------------------------------
// K2: fused forward. LDS: Hs 67,584 + WTs 65,536 = 133,120 B (red overlays WTs)
// ---------------------------------------------------------------------------
__global__ __launch_bounds__(1024, 4)
void ecnr_fwd(const float* __restrict__ x,
              const int*   __restrict__ mlp_idx,
              const int*   __restrict__ block_idx,
              const float* __restrict__ latent,
              const float* __restrict__ bias0, const float* __restrict__ bias1,
              const float* __restrict__ bias2, const float* __restrict__ bias3,
              const u16* __restrict__ wpl1, const u16* __restrict__ wpl2,
              const u16* __restrict__ w0pl, const float* __restrict__ w3f,
              float* __restrict__ out)
{
    __shared__ __attribute__((aligned(16))) u32 Hs[128 * 132]; // packed H [m][k], stride 132
    __shared__ __attribute__((aligned(16))) u16 WTs[32768];    // lo|hi chunk-major planes

    const int t  = threadIdx.x;
    const int b  = blockIdx.x & 255;       // tiles of one sample share an XCD
    const int p0 = (blockIdx.x >> 8) * 128;
    const int m  = mlp_idx[b];

    const int l  = t & 63, w = t >> 6;
    const int q  = l >> 5, ln = l & 31;
    const int pt = w & 3, nt = w >> 2;
    const int mrow = pt * 32 + ln;
    const int nn   = nt * 32 + ln;

    // ---- issue all consumer loads BEFORE the DMA (vmcnt ordering) ----
    const float* xp = x + (size_t)(b * 2048 + p0 + mrow) * 3;
    const float xv0 = xp[0], xv1 = xp[1], xv2 = xp[2];
    const u16* w0p = w0pl + (size_t)m * 4096;
    const v4u w0lo = *(const v4u*)(w0p + q * 1024 + nn * 8);
    const v4u w0hi = *(const v4u*)(w0p + 2048 + q * 1024 + nn * 8);
    const float* zp = latent + ((size_t)m * 8 + block_idx[b]) * 13;
    float zr[8];
    {
        const int zb0 = q * 5;
        #pragma unroll
        for (int jj = 0; jj < 8; ++jj) zr[jj] = zp[zb0 + jj];
    }
    const float bias0v = bias0[m * 128 + nn];
    const float bias1v = bias1[m * 128 + nn];
    const float bias2v = bias2[m * 128 + nn];

    // ---- WT(L1) DMA: streams while L0 computes ----
    {
        const u32* g = (const u32*)(wpl1 + (size_t)m * 32768);
        #pragma unroll
        for (int i = 0; i < 4; ++i)
            dma16(g + (w * 4 + i) * 256 + l * 4, (u32*)WTs + (w * 4 + i) * 256);
    }

    // ---- layer 0: A and B fully in registers ----
    {
        v4u uA, uB;
        uA[0] = pack2(q ? zr[0] : xv0);
        uA[1] = pack2(q ? zr[1] : xv1);
        uA[2] = pack2(q ? zr[2] : xv2);
        uA[3] = pack2(q ? zr[3] : zr[0]);
        #pragma unroll
        for (int jj = 0; jj < 4; ++jj) uB[jj] = pack2(q ? zr[4 + jj] : zr[1 + jj]);
        v8bf a0, a1;
        unpack8p(uA, uB, a0, a1);
        const v8bf bb0 = __builtin_bit_cast(v8bf, w0lo);
        const v8bf bb1 = __builtin_bit_cast(v8bf, w0hi);
        v16f acc;
        #pragma unroll
        for (int r = 0; r < 16; ++r) acc[r] = bias0v;
        acc = MFMA(a0, bb0, acc);
        acc = MFMA(a1, bb0, acc);
        acc = MFMA(a0, bb1, acc);
        acc = MFMA(a1, bb1, acc);
        u32* hw = Hs + (pt * 32 + 4 * q) * 132 + nn;
        #pragma unroll
        for (int r = 0; r < 16; ++r)
            hw[((r & 3) + 8 * (r >> 2)) * 132] = pack2(sin_omega(acc[r]));
    }
    __syncthreads();  // B1: Hs(L0) visible, WT(L1) DMA drained

    // ---- layers 1,2: base + immediate-offset reads only ----
    const u32* Ab = Hs + mrow * 132 + q * 8;         // A: imm = kc*64 B (+16)
    const u16* Bb = WTs + q * 1024 + nn * 8;         // B: imm = kc*4096 B (+32768 hi)
    u32* hw = Hs + (pt * 32 + 4 * q) * 132 + nn;
    #pragma unroll
    for (int L = 0; L < 2; ++L) {
        const float bv = L ? bias2v : bias1v;
        v16f acc;
        #pragma unroll
        for (int r = 0; r < 16; ++r) acc[r] = bv;
        #pragma unroll
        for (int kc = 0; kc < 8; ++kc) {
            const v4u uA = *(const v4u*)(Ab + kc * 16);
            const v4u uB = *(const v4u*)(Ab + kc * 16 + 4);
            const v8bf bb0 = *(const v8bf*)(Bb + kc * 2048);
            const v8bf bb1 = *(const v8bf*)(Bb + kc * 2048 + 16384);
            v8bf a0, a1;
            unpack8p(uA, uB, a0, a1);
            acc = MFMA(a0, bb0, acc);
            acc = MFMA(a1, bb0, acc);
            acc = MFMA(a0, bb1, acc);
            acc = MFMA(a1, bb1, acc);
        }
        __syncthreads();  // B2/B4: all H & WT reads of this layer done
        if (L == 0) {     // WT(L2) DMA streams under the sin epilogue
            const u32* g = (const u32*)(wpl2 + (size_t)m * 32768);
            #pragma unroll
            for (int i = 0; i < 4; ++i)
                dma16(g + (w * 4 + i) * 256 + l * 4, (u32*)WTs + (w * 4 + i) * 256);
        }
        #pragma unroll
        for (int r = 0; r < 16; ++r)
            hw[((r & 3) + 8 * (r >> 2)) * 132] = pack2(sin_omega(acc[r]));
        __syncthreads();  // B3/B5: Hs(L) visible (+DMA drained)
    }

    // ---- layer 3: [128x128]@[128x1] + bias (8-way k-split, red in WTs) ----
    {
        const int p = t & 127, qk = t >> 7;
        const u32* hp = Hs + p * 132 + qk * 16;
        const float* wq = w3f + (size_t)m * 128 + qk * 16;
        float s = 0.f;
        #pragma unroll
        for (int i = 0; i < 4; ++i) {
            const v4u uh = *(const v4u*)(hp + 4 * i);
            s = __builtin_fmaf(upk(uh[0]), wq[4 * i + 0], s);
            s = __builtin_fmaf(upk(uh[1]), wq[4 * i + 1], s);
            s = __builtin_fmaf(upk(uh[2]), wq[4 * i + 2], s);
            s = __builtin_fmaf(upk(uh[3]), wq[4 * i + 3], s);
        }
        ((float*)WTs)[qk * 128 + p] = s;
    }
    __syncthreads();  // B6

    if (t < 128) {
        const float* red = (const float*)WTs;
        float o = bias3[m];
        #pragma unroll
        for (int qk = 0; qk < 8; ++qk) o += red[qk * 128 + t];
        out[(size_t)b * 2048 + p0 + t] = o;
    }
}

extern "C" void kernel_launch(void* const* d_in, const int* in_sizes, int n_in,
                              void* d_out, int out_size, void* d_ws, size_t ws_size,
                              hipStream_t stream) {
    (void)in_sizes; (void)n_in; (void)out_size; (void)ws_size;
    u16*   wpl1 = (u16*)d_ws;                         // 16 MB
    u16*   wpl2 = wpl1 + (size_t)256 * 32768;         // 16 MB
    u16*   w0pl = wpl2 + (size_t)256 * 32768;         // 2 MB
    float* w3f  = (float*)(w0pl + (size_t)256 * 4096); // 128 KB

    ecnr_dequant<<<2304, 256, 0, stream>>>(
        (const float*)d_in[4],  (const int*)d_in[5],
        (const float*)d_in[7],  (const int*)d_in[8],
        (const float*)d_in[10], (const int*)d_in[11],
        (const float*)d_in[13], (const int*)d_in[14],
        wpl1, wpl2, w0pl, w3f);

    ecnr_fwd<<<4096, 1024, 0, stream>>>(
        (const float*)d_in[0], (const int*)d_in[1], (const int*)d_in[2],
        (const float*)d_in[3],
        (const float*)d_in[6], (const float*)d_in[9],
        (const float*)d_in[12], (const float*)d_in[15],
        wpl1, wpl2, w0pl, w3f,
        (float*)d_out);
}

// Round 7
// 291.723 us; speedup vs baseline: 1.9389x; 1.0078x over previous
//
#include <hip/hip_runtime.h>

// ECNR forward, R7.
//  K1 ecnr_dequant (unchanged from R6): W (L1,L2) -> two pre-split bf16
//     planes (lo,hi) per layer, CHUNK-MAJOR [16 k-chunks][128 n][8 k];
//     W0 likewise ([2][128][8]); w3 as f32.
//  K2 ecnr_fwd: 8192 blocks (= 32 tiles x 256 samples) x 512 thr (8 waves,
//     2pt x 4nt 32x32 tiles). B fragments read DIRECTLY from global
//     (coalesced dwordx4, L2/L3-resident planes) -> no WTs LDS, no DMA.
//     LDS = Hs[64][132] + red = 35.8 KB -> 4 blocks/CU, 32 waves/CU.
//     bf16x2 split MFMA (4 products). 6 barriers, 8-wave each.

typedef unsigned int u32;
typedef unsigned short u16;
typedef __bf16 v8bf  __attribute__((ext_vector_type(8)));
typedef float  v16f  __attribute__((ext_vector_type(16)));
typedef u32    v4u   __attribute__((ext_vector_type(4)));

#define MFMA(a, b, c) __builtin_amdgcn_mfma_f32_32x32x16_bf16(a, b, c, 0, 0, 0)

// sin(30*pre) = v_sin(fract(pre * 30/2pi)); v_sin takes revolutions.
__device__ __forceinline__ float sin_omega(float pre) {
    float rev = pre * 4.774648292756860f;     // 30/(2*pi)
    rev -= __builtin_floorf(rev);             // fract -> [0,1)
    return __builtin_amdgcn_sinf(rev);
}

// fp32 -> packed bf16x2 (low16 = leading split, high16 = residual)
__device__ __forceinline__ u32 pack2(float c) {
    __bf16 b0 = (__bf16)c;
    float  f0 = (float)b0;
    __bf16 b1 = (__bf16)(c - f0);
    return (u32)__builtin_bit_cast(u16, b0) |
           ((u32)__builtin_bit_cast(u16, b1) << 16);
}

__device__ __forceinline__ float upk(u32 u) {
    return __builtin_bit_cast(float, u << 16) +
           __builtin_bit_cast(float, u & 0xffff0000u);
}

// two v4u of packed bf16x2 (k ascending) -> split fragments via v_perm_b32
__device__ __forceinline__ void unpack8p(v4u A, v4u B, v8bf& a0, v8bf& a1) {
    v4u lo, hi;
    lo[0] = __builtin_amdgcn_perm(A[1], A[0], 0x05040100u);
    lo[1] = __builtin_amdgcn_perm(A[3], A[2], 0x05040100u);
    lo[2] = __builtin_amdgcn_perm(B[1], B[0], 0x05040100u);
    lo[3] = __builtin_amdgcn_perm(B[3], B[2], 0x05040100u);
    hi[0] = __builtin_amdgcn_perm(A[1], A[0], 0x07060302u);
    hi[1] = __builtin_amdgcn_perm(A[3], A[2], 0x07060302u);
    hi[2] = __builtin_amdgcn_perm(B[1], B[0], 0x07060302u);
    hi[3] = __builtin_amdgcn_perm(B[3], B[2], 0x07060302u);
    a0 = __builtin_bit_cast(v8bf, lo);
    a1 = __builtin_bit_cast(v8bf, hi);
}

// ---------------------------------------------------------------------------
// K1: dequant (unchanged from R6). blockIdx = m*9 + j.
// Plane layout per mlp (u16): lo[16384] | hi[16384]; element (n,k) at
// (k>>3)*1024 + n*8 + (k&7).
// ---------------------------------------------------------------------------
__global__ __launch_bounds__(256)
void ecnr_dequant(const float* __restrict__ cent0, const int* __restrict__ lab0,
                  const float* __restrict__ cent1, const int* __restrict__ lab1,
                  const float* __restrict__ cent2, const int* __restrict__ lab2,
                  const float* __restrict__ cent3, const int* __restrict__ lab3,
                  u16* __restrict__ wpl1, u16* __restrict__ wpl2,
                  u16* __restrict__ w0pl, float* __restrict__ w3f)
{
    __shared__ u32 cpk[256];
    __shared__ u32 stage[128 * 33];
    const int t = threadIdx.x;
    const int m = blockIdx.x / 9;
    const int j = blockIdx.x - m * 9;

    if (j < 8) {
        const int L  = j >> 2;
        const int nt = j & 3;
        cpk[t] = pack2((L ? cent2 : cent1)[t]);
        __syncthreads();
        const int* lab = (L ? lab2 : lab1) + (size_t)m * 16384;
        #pragma unroll
        for (int i = 0; i < 16; ++i) {
            const int idx = i * 256 + t;
            const int n = idx & 31, k = idx >> 5;
            stage[k * 33 + n] = cpk[lab[k * 128 + nt * 32 + n]];
        }
        __syncthreads();
        u16* base = (L ? wpl2 : wpl1) + (size_t)m * 32768;
        const int n  = t & 31;
        const int ng = nt * 32 + n;
        #pragma unroll
        for (int s = 0; s < 2; ++s) {
            const int c = (t >> 5) + 8 * s;
            u32 u[8];
            #pragma unroll
            for (int jj = 0; jj < 8; ++jj) u[jj] = stage[(8 * c + jj) * 33 + n];
            v4u lo, hi;
            #pragma unroll
            for (int r = 0; r < 4; ++r) {
                lo[r] = __builtin_amdgcn_perm(u[2*r+1], u[2*r], 0x05040100u);
                hi[r] = __builtin_amdgcn_perm(u[2*r+1], u[2*r], 0x07060302u);
            }
            *(v4u*)(base + c * 1024 + ng * 8)         = lo;
            *(v4u*)(base + 16384 + c * 1024 + ng * 8) = hi;
        }
    } else {
        cpk[t] = pack2(cent0[t]);
        __syncthreads();
        const int* lab = lab0 + (size_t)m * 2048;
        #pragma unroll
        for (int i = 0; i < 8; ++i) {
            const int idx = i * 256 + t;
            const int n = idx & 127, k = idx >> 7;
            stage[k * 129 + n] = cpk[lab[idx]];
        }
        __syncthreads();
        {
            const int c = t >> 7, n = t & 127;   // [2 chunks][128 n]
            u32 u[8];
            #pragma unroll
            for (int jj = 0; jj < 8; ++jj) u[jj] = stage[(8 * c + jj) * 129 + n];
            v4u lo, hi;
            #pragma unroll
            for (int r = 0; r < 4; ++r) {
                lo[r] = __builtin_amdgcn_perm(u[2*r+1], u[2*r], 0x05040100u);
                hi[r] = __builtin_amdgcn_perm(u[2*r+1], u[2*r], 0x07060302u);
            }
            u16* b0 = w0pl + (size_t)m * 4096;
            *(v4u*)(b0 + c * 1024 + n * 8)        = lo;
            *(v4u*)(b0 + 2048 + c * 1024 + n * 8) = hi;
        }
        if (t < 128) w3f[(size_t)m * 128 + t] = cent3[lab3[(size_t)m * 128 + t]];
    }
}

// ---------------------------------------------------------------------------
// K2: fused forward. LDS: Hs 33,792 + red 2,048 = 35,840 B -> 4 blocks/CU.
// ---------------------------------------------------------------------------
__global__ __launch_bounds__(512, 8)
void ecnr_fwd(const float* __restrict__ x,
              const int*   __restrict__ mlp_idx,
              const int*   __restrict__ block_idx,
              const float* __restrict__ latent,
              const float* __restrict__ bias0, const float* __restrict__ bias1,
              const float* __restrict__ bias2, const float* __restrict__ bias3,
              const u16* __restrict__ wpl1, const u16* __restrict__ wpl2,
              const u16* __restrict__ w0pl, const float* __restrict__ w3f,
              float* __restrict__ out)
{
    __shared__ __attribute__((aligned(16))) u32   Hs[64 * 132]; // packed H [m][k]
    __shared__ __attribute__((aligned(16))) float red[8 * 64];

    const int t  = threadIdx.x;
    const int b  = blockIdx.x & 255;       // sample -> fixed XCD across tiles
    const int p0 = (blockIdx.x >> 8) * 64;
    const int m  = mlp_idx[b];

    const int l  = t & 63, w = t >> 6;     // lane, wave 0..7
    const int q  = l >> 5, ln = l & 31;
    const int pt = w & 1, nt = w >> 1;     // 2 x 4 grid of 32x32 tiles
    const int mrow = pt * 32 + ln;
    const int nn   = nt * 32 + ln;

    // ---- setup loads (all global, no LDS dependency) ----
    const float* xp = x + (size_t)(b * 2048 + p0 + mrow) * 3;
    const float xv0 = xp[0], xv1 = xp[1], xv2 = xp[2];
    const u16* w0p = w0pl + (size_t)m * 4096 + q * 1024 + nn * 8;
    const v4u w0lo = *(const v4u*)(w0p);
    const v4u w0hi = *(const v4u*)(w0p + 2048);
    const float* zp = latent + ((size_t)m * 8 + block_idx[b]) * 13;
    float zr[8];
    #pragma unroll
    for (int jj = 0; jj < 8; ++jj) zr[jj] = zp[q * 5 + jj];
    const float bias0v = bias0[m * 128 + nn];
    const float bias1v = bias1[m * 128 + nn];
    const float bias2v = bias2[m * 128 + nn];

    // ---- layer 0: A and B fully in registers ----
    u32* hw = Hs + (pt * 32 + 4 * q) * 132 + nn;
    {
        v4u uA, uB;
        uA[0] = pack2(q ? zr[0] : xv0);
        uA[1] = pack2(q ? zr[1] : xv1);
        uA[2] = pack2(q ? zr[2] : xv2);
        uA[3] = pack2(q ? zr[3] : zr[0]);
        #pragma unroll
        for (int jj = 0; jj < 4; ++jj) uB[jj] = pack2(q ? zr[4 + jj] : zr[1 + jj]);
        v8bf a0, a1;
        unpack8p(uA, uB, a0, a1);
        const v8bf bb0 = __builtin_bit_cast(v8bf, w0lo);
        const v8bf bb1 = __builtin_bit_cast(v8bf, w0hi);
        v16f acc;
        #pragma unroll
        for (int r = 0; r < 16; ++r) acc[r] = bias0v;
        acc = MFMA(a0, bb0, acc);
        acc = MFMA(a1, bb0, acc);
        acc = MFMA(a0, bb1, acc);
        acc = MFMA(a1, bb1, acc);
        #pragma unroll
        for (int r = 0; r < 16; ++r)
            hw[((r & 3) + 8 * (r >> 2)) * 132] = pack2(sin_omega(acc[r]));
    }
    __syncthreads();  // B1: Hs(L0) visible

    // ---- layers 1,2: A from LDS (imm offsets), B direct from global ----
    const u32* Ab = Hs + mrow * 132 + q * 8;
    #pragma unroll
    for (int L = 0; L < 2; ++L) {
        const u16* Bp = (L ? wpl2 : wpl1) + (size_t)m * 32768 + q * 1024 + nn * 8;
        const float bv = L ? bias2v : bias1v;
        v16f acc;
        #pragma unroll
        for (int r = 0; r < 16; ++r) acc[r] = bv;
        #pragma unroll
        for (int kc = 0; kc < 8; ++kc) {
            const v4u uA = *(const v4u*)(Ab + kc * 16);
            const v4u uB = *(const v4u*)(Ab + kc * 16 + 4);
            const v8bf bb0 = *(const v8bf*)(Bp + kc * 2048);
            const v8bf bb1 = *(const v8bf*)(Bp + kc * 2048 + 16384);
            v8bf a0, a1;
            unpack8p(uA, uB, a0, a1);
            acc = MFMA(a0, bb0, acc);
            acc = MFMA(a1, bb0, acc);
            acc = MFMA(a0, bb1, acc);
            acc = MFMA(a1, bb1, acc);
        }
        __syncthreads();  // B2/B4: all Hs reads of this layer done
        #pragma unroll
        for (int r = 0; r < 16; ++r)
            hw[((r & 3) + 8 * (r >> 2)) * 132] = pack2(sin_omega(acc[r]));
        __syncthreads();  // B3/B5: Hs(L) visible
    }

    // ---- layer 3: [64x128]@[128x1] + bias (8-way k-split) ----
    {
        const int p = t & 63, qk = t >> 6;
        const u32* hp = Hs + p * 132 + qk * 16;
        const float* wq = w3f + (size_t)m * 128 + qk * 16;
        float s = 0.f;
        #pragma unroll
        for (int i = 0; i < 4; ++i) {
            const v4u uh = *(const v4u*)(hp + 4 * i);
            s = __builtin_fmaf(upk(uh[0]), wq[4 * i + 0], s);
            s = __builtin_fmaf(upk(uh[1]), wq[4 * i + 1], s);
            s = __builtin_fmaf(upk(uh[2]), wq[4 * i + 2], s);
            s = __builtin_fmaf(upk(uh[3]), wq[4 * i + 3], s);
        }
        red[qk * 64 + p] = s;
    }
    __syncthreads();  // B6

    if (t < 64) {
        float o = bias3[m];
        #pragma unroll
        for (int qk = 0; qk < 8; ++qk) o += red[qk * 64 + t];
        out[(size_t)b * 2048 + p0 + t] = o;
    }
}

extern "C" void kernel_launch(void* const* d_in, const int* in_sizes, int n_in,
                              void* d_out, int out_size, void* d_ws, size_t ws_size,
                              hipStream_t stream) {
    (void)in_sizes; (void)n_in; (void)out_size; (void)ws_size;
    u16*   wpl1 = (u16*)d_ws;                          // 16 MB
    u16*   wpl2 = wpl1 + (size_t)256 * 32768;          // 16 MB
    u16*   w0pl = wpl2 + (size_t)256 * 32768;          // 2 MB
    float* w3f  = (float*)(w0pl + (size_t)256 * 4096); // 128 KB

    ecnr_dequant<<<2304, 256, 0, stream>>>(
        (const float*)d_in[4],  (const int*)d_in[5],
        (const float*)d_in[7],  (const int*)d_in[8],
        (const float*)d_in[10], (const int*)d_in[11],
        (const float*)d_in[13], (const int*)d_in[14],
        wpl1, wpl2, w0pl, w3f);

    ecnr_fwd<<<8192, 512, 0, stream>>>(
        (const float*)d_in[0], (const int*)d_in[1], (const int*)d_in[2],
        (const float*)d_in[3],
        (const float*)d_in[6], (const float*)d_in[9],
        (const float*)d_in[12], (const float*)d_in[15],
        wpl1, wpl2, w0pl, w3f,
        (float*)d_out);
}